// Round 13
// baseline (394.545 us; speedup 1.0000x reference)
//
#include <hip/hip_runtime.h>
#include <hip/hip_fp16.h>
#include <math.h>

#define NN 50000
#define NE 800000
#define INF 128
#define H 64
#define ELLCAP 64
#define NPART 8
#define PSIZE ((NN + NPART - 1) / NPART)  // 6250
#define EPT 25                            // edges per thread per chunk
#define CHUNK (256 * EPT)                 // 6400
#define NCHUNK ((NE + CHUNK - 1) / CHUNK) // 125
#define CHUNK_A 63                        // prepA: chunks [0,63) ; prepB: [63,125)
#define NB_FILL_A (CHUNK_A * NPART)       // 504
#define NB_FILL_B ((NCHUNK - CHUNK_A) * NPART) // 496
#define NB_G ((NN + 63) / 64)             // 782
#define NB_HALF 12500                     // spmm blocks per column half
// packed fp16 weights: W1|W2|Wc1|Wc2|W3
#define WOFF_W1 0
#define WOFF_W2 8192
#define WOFF_WC1 12288
#define WOFF_WC2 24576
#define WOFF_W3 36864
#define WTOT 40960
#define NB_CVTW (WTOT / 2048)             // 20
#define NB_DINV 25                        // 25*2048 >= 50000

typedef _Float16 half8_t __attribute__((ext_vector_type(8)));
typedef float float4_t __attribute__((ext_vector_type(4)));

__device__ __forceinline__ half8_t load_cvt8(const float* p) {
  float4 a = *(const float4*)(p);
  float4 b = *(const float4*)(p + 4);
  half8_t h;
  h[0] = (_Float16)a.x; h[1] = (_Float16)a.y; h[2] = (_Float16)a.z; h[3] = (_Float16)a.w;
  h[4] = (_Float16)b.x; h[5] = (_Float16)b.y; h[6] = (_Float16)b.z; h[7] = (_Float16)b.w;
  return h;
}

// ---------------- fill device body (chunk range [c0,c1)) ----------------
// Plateau (R1-R5): scattered-atomic edge pass pinned at ~19 atomics/ns.
// R9/R10: do NOT co-schedule other memory-heavy work with it.
// R12: split into two dispatches purely so sub-50us kernels surface in top-5.
__device__ __forceinline__ void fill_body(int bid, int c0,
                                          const int* __restrict__ src, const int* __restrict__ dst,
                                          int* __restrict__ cnt, unsigned short* __restrict__ ell) {
  int p = bid & (NPART - 1);
  int chunk = c0 + (bid >> 3);
  int lo = p * PSIZE, hi = lo + PSIZE;
  int base = chunk * CHUNK + threadIdx.x;
#pragma unroll
  for (int i = 0; i < EPT; ++i) {
    int e = base + i * 256;
    if (e < NE) {
      int d = __builtin_nontemporal_load(&dst[e]);
      if (d >= lo && d < hi) {
        int s = __builtin_nontemporal_load(&src[e]);
        int c = atomicAdd(&cnt[d], 1);
        if (c < ELLCAP) ell[((size_t)d << 6) + c] = (unsigned short)s;  // ids < 65536
      }
    }
  }
}

__global__ __launch_bounds__(256) void k_prepA(const int* __restrict__ src, const int* __restrict__ dst,
                                               int* __restrict__ cnt, unsigned short* __restrict__ ell,
                                               const float* __restrict__ W1, const float* __restrict__ W2,
                                               const float* __restrict__ Wc1, const float* __restrict__ Wc2,
                                               const float* __restrict__ W3, _Float16* __restrict__ w16) {
  int b = blockIdx.x;
  if (b < NB_FILL_A) {
    fill_body(b, 0, src, dst, cnt, ell);
  } else {
    int i0 = (b - NB_FILL_A) * 2048 + threadIdx.x * 8;
#pragma unroll
    for (int k = 0; k < 8; ++k) {
      int id = i0 + k;
      if (id < WTOT) {
        float v;
        if (id < WOFF_W2) v = W1[id];
        else if (id < WOFF_WC1) v = W2[id - WOFF_W2];
        else if (id < WOFF_WC2) v = Wc1[id - WOFF_WC1];
        else if (id < WOFF_W3) v = Wc2[id - WOFF_WC2];
        else v = W3[id - WOFF_W3];
        w16[id] = (_Float16)v;
      }
    }
  }
}

__global__ __launch_bounds__(256) void k_prepB(const int* __restrict__ src, const int* __restrict__ dst,
                                               int* __restrict__ cnt, unsigned short* __restrict__ ell) {
  fill_body(blockIdx.x, CHUNK_A, src, dst, cnt, ell);
}

// ---------------- mlp (+ dinv32 build in leading blocks) ----------------
// X0c = relu(relu(in@W1^T+b1)@W2^T+b2); h1 in LDS only; w16 pre-converted.
__global__ __launch_bounds__(256) void k_mlp(const float* __restrict__ in_feat,
                                             const _Float16* __restrict__ w16,
                                             const float* __restrict__ b1,
                                             const float* __restrict__ b2,
                                             const int* __restrict__ cnt,
                                             float* __restrict__ dinv32,
                                             _Float16* __restrict__ X0c, int N) {
  __shared__ _Float16 Hs[64][72];
  if (blockIdx.x < NB_DINV) {
    int i0 = blockIdx.x * 2048 + threadIdx.x * 8;
#pragma unroll
    for (int k = 0; k < 8; ++k) {
      int i = i0 + k;
      if (i < N) {
        int c = cnt[i];
        dinv32[i] = 1.0f / sqrtf((float)(c < 1 ? 1 : c));
      }
    }
    return;
  }
  const int tid = threadIdx.x;
  const int wave = tid >> 6;
  const int lane = tid & 63;
  const int m = lane & 15;
  const int quad = lane >> 4;
  const int rbase = (blockIdx.x - NB_DINV) * 64 + wave * 16;
  int arow = rbase + m;
  arow = arow < N ? arow : N - 1;
  const float* Ap = in_feat + (size_t)arow * INF + quad * 8;
  const _Float16* B1 = w16 + WOFF_W1 + (size_t)m * INF + quad * 8;
  float4_t acc[4] = {{0.f,0.f,0.f,0.f},{0.f,0.f,0.f,0.f},{0.f,0.f,0.f,0.f},{0.f,0.f,0.f,0.f}};
#pragma unroll
  for (int k0 = 0; k0 < INF; k0 += 32) {
    half8_t a = load_cvt8(Ap + k0);
    half8_t b0 = *(const half8_t*)(B1 + k0);
    half8_t b1f = *(const half8_t*)(B1 + 16 * INF + k0);
    half8_t b2f = *(const half8_t*)(B1 + 32 * INF + k0);
    half8_t b3f = *(const half8_t*)(B1 + 48 * INF + k0);
    acc[0] = __builtin_amdgcn_mfma_f32_16x16x32_f16(a, b0, acc[0], 0, 0, 0);
    acc[1] = __builtin_amdgcn_mfma_f32_16x16x32_f16(a, b1f, acc[1], 0, 0, 0);
    acc[2] = __builtin_amdgcn_mfma_f32_16x16x32_f16(a, b2f, acc[2], 0, 0, 0);
    acc[3] = __builtin_amdgcn_mfma_f32_16x16x32_f16(a, b3f, acc[3], 0, 0, 0);
  }
#pragma unroll
  for (int i = 0; i < 4; ++i)
#pragma unroll
    for (int t = 0; t < 4; ++t)
      Hs[wave * 16 + quad * 4 + i][t * 16 + m] = (_Float16)fmaxf(acc[t][i] + b1[t * 16 + m], 0.f);
  __syncthreads();
  const _Float16* Ap2 = &Hs[wave * 16 + m][quad * 8];
  const _Float16* B2 = w16 + WOFF_W2 + (size_t)m * H + quad * 8;
  float4_t acc2[4] = {{0.f,0.f,0.f,0.f},{0.f,0.f,0.f,0.f},{0.f,0.f,0.f,0.f},{0.f,0.f,0.f,0.f}};
#pragma unroll
  for (int k0 = 0; k0 < H; k0 += 32) {
    half8_t a = *(const half8_t*)(Ap2 + k0);
    half8_t b0 = *(const half8_t*)(B2 + k0);
    half8_t b1f = *(const half8_t*)(B2 + 16 * H + k0);
    half8_t b2f = *(const half8_t*)(B2 + 32 * H + k0);
    half8_t b3f = *(const half8_t*)(B2 + 48 * H + k0);
    acc2[0] = __builtin_amdgcn_mfma_f32_16x16x32_f16(a, b0, acc2[0], 0, 0, 0);
    acc2[1] = __builtin_amdgcn_mfma_f32_16x16x32_f16(a, b1f, acc2[1], 0, 0, 0);
    acc2[2] = __builtin_amdgcn_mfma_f32_16x16x32_f16(a, b2f, acc2[2], 0, 0, 0);
    acc2[3] = __builtin_amdgcn_mfma_f32_16x16x32_f16(a, b3f, acc2[3], 0, 0, 0);
  }
#pragma unroll
  for (int i = 0; i < 4; ++i) {
    int rr = rbase + quad * 4 + i;
    if (rr < N) {
#pragma unroll
      for (int t = 0; t < 4; ++t)
        X0c[((size_t)rr << 6) + t * 16 + m] = (_Float16)fmaxf(acc2[t][i] + b2[t * 16 + m], 0.f);
    }
  }
}

// ---------------- SpMM: wave-per-node, COLUMN-SPLIT halves for L2 residency ----------------
// R12: blocks [0,NB_HALF) gather cols 0..31, [NB_HALF,2*NB_HALF) cols 32..63.
// Dispatch-order phasing makes the hot gather set 3.2 MB per phase -> fits one
// XCD L2 (table 6.4 MB did not). 16 edge groups/wave: deg<=16 gathers in ONE
// load instruction. Per-edge scale via precomputed dinv32 (200 KB, L2-hot).
// outc[n] = alpha*dinv32[n]*sum_s dinv32[s]*table[s]  (- auxc[n] if use_aux).
__global__ __launch_bounds__(256) void k_spmm(const _Float16* __restrict__ table,
                                              const _Float16* __restrict__ auxc,
                                              _Float16* __restrict__ outc,
                                              const int* __restrict__ cnt,
                                              const float* __restrict__ dinv32,
                                              const unsigned short* __restrict__ ell,
                                              float alpha, int use_aux, int N) {
  int bid = blockIdx.x;
  int half = bid >= NB_HALF ? 1 : 0;
  int nb = half ? bid - NB_HALF : bid;
  int wid = (nb * 256 + threadIdx.x) >> 6;
  if (wid >= N) return;
  int lane = threadIdx.x & 63;
  int g = lane >> 2;                     // edge group 0..15
  int c8 = half * 32 + (lane & 3) * 8;   // column oct base within half
  int deg0 = cnt[wid];
  int deg = deg0 < ELLCAP ? deg0 : ELLCAP;
  const unsigned short* row = ell + ((size_t)wid << 6);

  float acc[8] = {0.f, 0.f, 0.f, 0.f, 0.f, 0.f, 0.f, 0.f};
  for (int j = g; j < deg; j += 16) {
    int s = row[j];
    float d = dinv32[s];
    half8_t v = *(const half8_t*)(table + ((size_t)s << 6) + c8);
#pragma unroll
    for (int k = 0; k < 8; ++k) acc[k] = fmaf(d, (float)v[k], acc[k]);
  }
  // reduce across the 16 edge groups (lanes xor 4,8,16,32)
#pragma unroll
  for (int k = 0; k < 8; ++k) {
    acc[k] += __shfl_xor(acc[k], 4);
    acc[k] += __shfl_xor(acc[k], 8);
    acc[k] += __shfl_xor(acc[k], 16);
    acc[k] += __shfl_xor(acc[k], 32);
  }
  if (g == 0) {  // lanes 0..3 cover the 32 cols of this half
    float a = alpha * dinv32[wid];
    float r[8];
#pragma unroll
    for (int k = 0; k < 8; ++k) r[k] = a * acc[k];
    if (use_aux) {
      half8_t x = *(const half8_t*)(auxc + ((size_t)wid << 6) + c8);
#pragma unroll
      for (int k = 0; k < 8; ++k) r[k] -= (float)x[k];
    }
    half8_t ro;
#pragma unroll
    for (int k = 0; k < 8; ++k) ro[k] = (_Float16)r[k];
    *(half8_t*)(outc + ((size_t)wid << 6) + c8) = ro;
  }
}

// ---------------- conv1 linear: Y0c = relu([A0|A1|A2]@Wc1^T + bc1), compact in/out ----------------
__global__ __launch_bounds__(256) void k_gemm192(const _Float16* __restrict__ A0,
                                                 const _Float16* __restrict__ A1,
                                                 const _Float16* __restrict__ A2,
                                                 const _Float16* __restrict__ B,  // [64,192] fp16
                                                 const float* __restrict__ bias,
                                                 _Float16* __restrict__ outc, int N) {
  const int tid = threadIdx.x;
  const int wave = tid >> 6;
  const int lane = tid & 63;
  const int m = lane & 15;
  const int quad = lane >> 4;
  const int rbase = blockIdx.x * 64 + wave * 16;
  int arow = rbase + m;
  arow = arow < N ? arow : N - 1;
  const size_t ro = ((size_t)arow << 6) + quad * 8;
  const _Float16* Bp = B + (size_t)m * 192 + quad * 8;
  float4_t acc[4] = {{0.f,0.f,0.f,0.f},{0.f,0.f,0.f,0.f},{0.f,0.f,0.f,0.f},{0.f,0.f,0.f,0.f}};
#pragma unroll
  for (int k0 = 0; k0 < 192; k0 += 32) {
    half8_t a;
    if (k0 < 64) a = *(const half8_t*)(A0 + ro + k0);
    else if (k0 < 128) a = *(const half8_t*)(A1 + ro + (k0 - 64));
    else a = *(const half8_t*)(A2 + ro + (k0 - 128));
    half8_t b0 = *(const half8_t*)(Bp + k0);
    half8_t b1f = *(const half8_t*)(Bp + 16 * 192 + k0);
    half8_t b2f = *(const half8_t*)(Bp + 32 * 192 + k0);
    half8_t b3f = *(const half8_t*)(Bp + 48 * 192 + k0);
    acc[0] = __builtin_amdgcn_mfma_f32_16x16x32_f16(a, b0, acc[0], 0, 0, 0);
    acc[1] = __builtin_amdgcn_mfma_f32_16x16x32_f16(a, b1f, acc[1], 0, 0, 0);
    acc[2] = __builtin_amdgcn_mfma_f32_16x16x32_f16(a, b2f, acc[2], 0, 0, 0);
    acc[3] = __builtin_amdgcn_mfma_f32_16x16x32_f16(a, b3f, acc[3], 0, 0, 0);
  }
#pragma unroll
  for (int i = 0; i < 4; ++i) {
    int rr = rbase + quad * 4 + i;
    if (rr < N) {
#pragma unroll
      for (int t = 0; t < 4; ++t)
        outc[((size_t)rr << 6) + t * 16 + m] = (_Float16)fmaxf(acc[t][i] + bias[t * 16 + m], 0.f);
    }
  }
}

// ---------------- fused tail (row-local, NO gather): conv2-linear -> W3 -> head ----------------
__global__ __launch_bounds__(256) void k_tail(const _Float16* __restrict__ A0,
                                              const _Float16* __restrict__ A1,
                                              const _Float16* __restrict__ A2,
                                              const _Float16* __restrict__ w16,
                                              const float* __restrict__ bc2,
                                              const float* __restrict__ b3,
                                              const float* __restrict__ W4,
                                              const float* __restrict__ b4,
                                              float* __restrict__ out, int N) {
  __shared__ _Float16 Hs2[64][72];
  __shared__ float Hs3[64][65];
  const int tid = threadIdx.x;
  const int wave = tid >> 6;
  const int lane = tid & 63;
  const int m = lane & 15;
  const int quad = lane >> 4;
  const int rbase = blockIdx.x * 64 + wave * 16;
  int arow = rbase + m;
  arow = arow < N ? arow : N - 1;
  {
    const size_t ro = ((size_t)arow << 6) + quad * 8;
    const _Float16* Bp = w16 + WOFF_WC2 + (size_t)m * 192 + quad * 8;
    float4_t acc[4] = {{0.f,0.f,0.f,0.f},{0.f,0.f,0.f,0.f},{0.f,0.f,0.f,0.f},{0.f,0.f,0.f,0.f}};
#pragma unroll
    for (int k0 = 0; k0 < 192; k0 += 32) {
      half8_t a;
      if (k0 < 64) a = *(const half8_t*)(A0 + ro + k0);
      else if (k0 < 128) a = *(const half8_t*)(A1 + ro + (k0 - 64));
      else a = *(const half8_t*)(A2 + ro + (k0 - 128));
      half8_t b0 = *(const half8_t*)(Bp + k0);
      half8_t b1f = *(const half8_t*)(Bp + 16 * 192 + k0);
      half8_t b2f = *(const half8_t*)(Bp + 32 * 192 + k0);
      half8_t b3f = *(const half8_t*)(Bp + 48 * 192 + k0);
      acc[0] = __builtin_amdgcn_mfma_f32_16x16x32_f16(a, b0, acc[0], 0, 0, 0);
      acc[1] = __builtin_amdgcn_mfma_f32_16x16x32_f16(a, b1f, acc[1], 0, 0, 0);
      acc[2] = __builtin_amdgcn_mfma_f32_16x16x32_f16(a, b2f, acc[2], 0, 0, 0);
      acc[3] = __builtin_amdgcn_mfma_f32_16x16x32_f16(a, b3f, acc[3], 0, 0, 0);
    }
#pragma unroll
    for (int i = 0; i < 4; ++i)
#pragma unroll
      for (int t = 0; t < 4; ++t)
        Hs2[wave * 16 + quad * 4 + i][t * 16 + m] =
            (_Float16)fmaxf(acc[t][i] + bc2[t * 16 + m], 0.f);
  }
  __syncthreads();
  {
    const _Float16* Ap = &Hs2[wave * 16 + m][quad * 8];
    const _Float16* Bp = w16 + WOFF_W3 + (size_t)m * H + quad * 8;
    float4_t acc[4] = {{0.f,0.f,0.f,0.f},{0.f,0.f,0.f,0.f},{0.f,0.f,0.f,0.f},{0.f,0.f,0.f,0.f}};
#pragma unroll
    for (int k0 = 0; k0 < H; k0 += 32) {
      half8_t a = *(const half8_t*)(Ap + k0);
      half8_t b0 = *(const half8_t*)(Bp + k0);
      half8_t b1f = *(const half8_t*)(Bp + 16 * H + k0);
      half8_t b2f = *(const half8_t*)(Bp + 32 * H + k0);
      half8_t b3f = *(const half8_t*)(Bp + 48 * H + k0);
      acc[0] = __builtin_amdgcn_mfma_f32_16x16x32_f16(a, b0, acc[0], 0, 0, 0);
      acc[1] = __builtin_amdgcn_mfma_f32_16x16x32_f16(a, b1f, acc[1], 0, 0, 0);
      acc[2] = __builtin_amdgcn_mfma_f32_16x16x32_f16(a, b2f, acc[2], 0, 0, 0);
      acc[3] = __builtin_amdgcn_mfma_f32_16x16x32_f16(a, b3f, acc[3], 0, 0, 0);
    }
#pragma unroll
    for (int i = 0; i < 4; ++i)
#pragma unroll
      for (int t = 0; t < 4; ++t)
        Hs3[wave * 16 + quad * 4 + i][t * 16 + m] = fmaxf(acc[t][i] + b3[t * 16 + m], 0.f);
  }
  __syncthreads();
  if (tid < 128) {
    int r = tid >> 1;
    int c = tid & 1;
    int row = blockIdx.x * 64 + r;
    if (row < N) {
      const float* w4 = W4 + c * 64;
      float s = 0.f;
#pragma unroll
      for (int k = 0; k < 64; ++k) s = fmaf(Hs3[r][k], w4[k], s);
      out[(size_t)row * 2 + c] = s + b4[c];
    }
  }
}

extern "C" void kernel_launch(void* const* d_in, const int* in_sizes, int n_in,
                              void* d_out, int out_size, void* d_ws, size_t ws_size,
                              hipStream_t stream) {
  const float* in_feat = (const float*)d_in[0];
  const int* src = (const int*)d_in[1];
  const int* dst = (const int*)d_in[2];
  const float* W1 = (const float*)d_in[3];
  const float* b1 = (const float*)d_in[4];
  const float* W2 = (const float*)d_in[5];
  const float* b2 = (const float*)d_in[6];
  const float* Wc1 = (const float*)d_in[7];
  const float* bc1 = (const float*)d_in[8];
  const float* Wc2 = (const float*)d_in[9];
  const float* bc2 = (const float*)d_in[10];
  const float* W3 = (const float*)d_in[11];
  const float* b3 = (const float*)d_in[12];
  const float* W4 = (const float*)d_in[13];
  const float* b4 = (const float*)d_in[14];
  float* out = (float*)d_out;

  char* ws = (char*)d_ws;
  size_t o = 0;
  auto carve = [&](size_t bytes) -> void* {
    o = (o + 255) & ~(size_t)255;
    void* p = ws + o;
    o += bytes;
    return p;
  };
  int* cnt = (int*)carve((size_t)NN * 4);
  unsigned short* ell = (unsigned short*)carve((size_t)NN * ELLCAP * 2);  // 6.4 MB u16
  float* dinv32 = (float*)carve((size_t)NN * 4);
  _Float16* w16 = (_Float16*)carve((size_t)WTOT * 2);
  _Float16* X0c = (_Float16*)carve((size_t)NN * H * 2);   // conv1 X0 (unscaled)
  _Float16* X1c = (_Float16*)carve((size_t)NN * H * 2);   // conv1 X1
  _Float16* X2c = (_Float16*)carve((size_t)NN * H * 2);   // conv1 X2
  _Float16* Y0c = (_Float16*)carve((size_t)NN * H * 2);   // conv2 X0 (= conv1 out)
  _Float16* Y1c = (_Float16*)carve((size_t)NN * H * 2);
  _Float16* Y2c = (_Float16*)carve((size_t)NN * H * 2);
  (void)ws_size; (void)in_sizes; (void)n_in; (void)out_size;

  const int NB_SP = 2 * NB_HALF;  // 25000

  hipMemsetAsync(cnt, 0, (size_t)NN * 4, stream);
  // fill (split for top-5 visibility) + weight cvt
  k_prepA<<<NB_FILL_A + NB_CVTW, 256, 0, stream>>>(src, dst, cnt, ell, W1, W2, Wc1, Wc2, W3, w16);
  k_prepB<<<NB_FILL_B, 256, 0, stream>>>(src, dst, cnt, ell);
  // dinv32 build + entry MLP -> X0c
  k_mlp<<<NB_DINV + NB_G, 256, 0, stream>>>(in_feat, w16, b1, b2, cnt, dinv32, X0c, NN);
  // conv1: X1 = -A.X0
  k_spmm<<<NB_SP, 256, 0, stream>>>(X0c, (const _Float16*)nullptr, X1c, cnt, dinv32, ell, -1.f, 0, NN);
  // conv1: X2 = -2*A.X1 - X0
  k_spmm<<<NB_SP, 256, 0, stream>>>(X1c, X0c, X2c, cnt, dinv32, ell, -2.f, 1, NN);
  // conv1 linear -> Y0c
  k_gemm192<<<NB_G, 256, 0, stream>>>(X0c, X1c, X2c, w16 + WOFF_WC1, bc1, Y0c, NN);
  // conv2: Y1 = -A.Y0
  k_spmm<<<NB_SP, 256, 0, stream>>>(Y0c, (const _Float16*)nullptr, Y1c, cnt, dinv32, ell, -1.f, 0, NN);
  // conv2: Y2 = -2*A.Y1 - Y0
  k_spmm<<<NB_SP, 256, 0, stream>>>(Y1c, Y0c, Y2c, cnt, dinv32, ell, -2.f, 1, NN);
  // fused tail: conv2-linear -> W3 -> head
  k_tail<<<NB_G, 256, 0, stream>>>(Y0c, Y1c, Y2c, w16, bc2, b3, W4, b4, out, NN);
}

// Round 14
// 305.992 us; speedup vs baseline: 1.2894x; 1.2894x over previous
//
#include <hip/hip_runtime.h>
#include <hip/hip_fp16.h>
#include <math.h>

#define NN 50000
#define NE 800000
#define INF 128
#define H 64
#define ELLCAP 64
#define NPART 8
#define PSIZE ((NN + NPART - 1) / NPART)  // 6250
#define EPT 25                            // edges per thread per chunk
#define CHUNK (256 * EPT)                 // 6400
#define NCHUNK ((NE + CHUNK - 1) / CHUNK) // 125
#define NB_FILL (NCHUNK * NPART)          // 1000
#define NB_G ((NN + 63) / 64)             // 782
// packed fp16 weights: W1|W2|Wc1|Wc2|W3
#define WOFF_W1 0
#define WOFF_W2 8192
#define WOFF_WC1 12288
#define WOFF_WC2 24576
#define WOFF_W3 36864
#define WTOT 40960
#define NB_CVTW (WTOT / 2048)             // 20
#define NB_DINV 25                        // 25*2048 >= 50000

typedef _Float16 half8_t __attribute__((ext_vector_type(8)));
typedef float float4_t __attribute__((ext_vector_type(4)));

__device__ __forceinline__ half8_t load_cvt8(const float* p) {
  float4 a = *(const float4*)(p);
  float4 b = *(const float4*)(p + 4);
  half8_t h;
  h[0] = (_Float16)a.x; h[1] = (_Float16)a.y; h[2] = (_Float16)a.z; h[3] = (_Float16)a.w;
  h[4] = (_Float16)b.x; h[5] = (_Float16)b.y; h[6] = (_Float16)b.z; h[7] = (_Float16)b.w;
  return h;
}

// ---------------- prep: fillell(u16) + weight-cvt ----------------
// Plateau (R1-R5): scattered-atomic edge pass pinned at ~19 atomics/ns (~50 us).
// R9/R10: do NOT co-schedule memory-heavy work with it. R12/R13: splitting it
// for profiler visibility cost ~+15 us + downstream noise -- keep it whole.
__global__ __launch_bounds__(256) void k_prep(const int* __restrict__ src, const int* __restrict__ dst,
                                              int* __restrict__ cnt, unsigned short* __restrict__ ell,
                                              const float* __restrict__ W1, const float* __restrict__ W2,
                                              const float* __restrict__ Wc1, const float* __restrict__ Wc2,
                                              const float* __restrict__ W3, _Float16* __restrict__ w16) {
  int b = blockIdx.x;
  if (b < NB_FILL) {
    int p = b & (NPART - 1);
    int chunk = b >> 3;
    int lo = p * PSIZE, hi = lo + PSIZE;
    int base = chunk * CHUNK + threadIdx.x;
#pragma unroll
    for (int i = 0; i < EPT; ++i) {
      int e = base + i * 256;
      if (e < NE) {
        int d = __builtin_nontemporal_load(&dst[e]);
        if (d >= lo && d < hi) {
          int s = __builtin_nontemporal_load(&src[e]);
          int c = atomicAdd(&cnt[d], 1);
          if (c < ELLCAP) ell[((size_t)d << 6) + c] = (unsigned short)s;  // ids < 65536
        }
      }
    }
  } else {
    int i0 = (b - NB_FILL) * 2048 + threadIdx.x * 8;
#pragma unroll
    for (int k = 0; k < 8; ++k) {
      int id = i0 + k;
      if (id < WTOT) {
        float v;
        if (id < WOFF_W2) v = W1[id];
        else if (id < WOFF_WC1) v = W2[id - WOFF_W2];
        else if (id < WOFF_WC2) v = Wc1[id - WOFF_WC1];
        else if (id < WOFF_W3) v = Wc2[id - WOFF_WC2];
        else v = W3[id - WOFF_W3];
        w16[id] = (_Float16)v;
      }
    }
  }
}

// ---------------- mlp (+ dinv32 build in leading blocks) ----------------
__global__ __launch_bounds__(256) void k_mlp(const float* __restrict__ in_feat,
                                             const _Float16* __restrict__ w16,
                                             const float* __restrict__ b1,
                                             const float* __restrict__ b2,
                                             const int* __restrict__ cnt,
                                             float* __restrict__ dinv32,
                                             _Float16* __restrict__ X0c, int N) {
  __shared__ _Float16 Hs[64][72];
  if (blockIdx.x < NB_DINV) {
    int i0 = blockIdx.x * 2048 + threadIdx.x * 8;
#pragma unroll
    for (int k = 0; k < 8; ++k) {
      int i = i0 + k;
      if (i < N) {
        int c = cnt[i];
        dinv32[i] = 1.0f / sqrtf((float)(c < 1 ? 1 : c));
      }
    }
    return;
  }
  const int tid = threadIdx.x;
  const int wave = tid >> 6;
  const int lane = tid & 63;
  const int m = lane & 15;
  const int quad = lane >> 4;
  const int rbase = (blockIdx.x - NB_DINV) * 64 + wave * 16;
  int arow = rbase + m;
  arow = arow < N ? arow : N - 1;
  const float* Ap = in_feat + (size_t)arow * INF + quad * 8;
  const _Float16* B1 = w16 + WOFF_W1 + (size_t)m * INF + quad * 8;
  float4_t acc[4] = {{0.f,0.f,0.f,0.f},{0.f,0.f,0.f,0.f},{0.f,0.f,0.f,0.f},{0.f,0.f,0.f,0.f}};
#pragma unroll
  for (int k0 = 0; k0 < INF; k0 += 32) {
    half8_t a = load_cvt8(Ap + k0);
    half8_t b0 = *(const half8_t*)(B1 + k0);
    half8_t b1f = *(const half8_t*)(B1 + 16 * INF + k0);
    half8_t b2f = *(const half8_t*)(B1 + 32 * INF + k0);
    half8_t b3f = *(const half8_t*)(B1 + 48 * INF + k0);
    acc[0] = __builtin_amdgcn_mfma_f32_16x16x32_f16(a, b0, acc[0], 0, 0, 0);
    acc[1] = __builtin_amdgcn_mfma_f32_16x16x32_f16(a, b1f, acc[1], 0, 0, 0);
    acc[2] = __builtin_amdgcn_mfma_f32_16x16x32_f16(a, b2f, acc[2], 0, 0, 0);
    acc[3] = __builtin_amdgcn_mfma_f32_16x16x32_f16(a, b3f, acc[3], 0, 0, 0);
  }
#pragma unroll
  for (int i = 0; i < 4; ++i)
#pragma unroll
    for (int t = 0; t < 4; ++t)
      Hs[wave * 16 + quad * 4 + i][t * 16 + m] = (_Float16)fmaxf(acc[t][i] + b1[t * 16 + m], 0.f);
  __syncthreads();
  const _Float16* Ap2 = &Hs[wave * 16 + m][quad * 8];
  const _Float16* B2 = w16 + WOFF_W2 + (size_t)m * H + quad * 8;
  float4_t acc2[4] = {{0.f,0.f,0.f,0.f},{0.f,0.f,0.f,0.f},{0.f,0.f,0.f,0.f},{0.f,0.f,0.f,0.f}};
#pragma unroll
  for (int k0 = 0; k0 < H; k0 += 32) {
    half8_t a = *(const half8_t*)(Ap2 + k0);
    half8_t b0 = *(const half8_t*)(B2 + k0);
    half8_t b1f = *(const half8_t*)(B2 + 16 * H + k0);
    half8_t b2f = *(const half8_t*)(B2 + 32 * H + k0);
    half8_t b3f = *(const half8_t*)(B2 + 48 * H + k0);
    acc2[0] = __builtin_amdgcn_mfma_f32_16x16x32_f16(a, b0, acc2[0], 0, 0, 0);
    acc2[1] = __builtin_amdgcn_mfma_f32_16x16x32_f16(a, b1f, acc2[1], 0, 0, 0);
    acc2[2] = __builtin_amdgcn_mfma_f32_16x16x32_f16(a, b2f, acc2[2], 0, 0, 0);
    acc2[3] = __builtin_amdgcn_mfma_f32_16x16x32_f16(a, b3f, acc2[3], 0, 0, 0);
  }
#pragma unroll
  for (int i = 0; i < 4; ++i) {
    int rr = rbase + quad * 4 + i;
    if (rr < N) {
#pragma unroll
      for (int t = 0; t < 4; ++t)
        X0c[((size_t)rr << 6) + t * 16 + m] = (_Float16)fmaxf(acc2[t][i] + b2[t * 16 + m], 0.f);
    }
  }
}

// ---------------- SpMM: wave-per-node, full-row gather (R13 lesson: NO column split --
// the table is compulsorily replicated into all 8 XCD L2s (~51 MB HBM/pass floor);
// splitting only doubles the index stream). 8 edge groups x half8; dual gathers in
// flight; dinv32 (200 KB, L2-hot) instead of per-edge cnt->cvt->rsqrt (VALU trim);
// nt index loads so the 6.4 MB once-read ELL stream doesn't evict table lines.
// outc[n] = alpha*dinv32[n]*sum_s dinv32[s]*table[s]  (- auxc[n] if use_aux).
__global__ __launch_bounds__(256) void k_spmm(const _Float16* __restrict__ table,
                                              const _Float16* __restrict__ auxc,
                                              _Float16* __restrict__ outc,
                                              const int* __restrict__ cnt,
                                              const float* __restrict__ dinv32,
                                              const unsigned short* __restrict__ ell,
                                              float alpha, int use_aux, int N) {
  int wid = (blockIdx.x * 256 + threadIdx.x) >> 6;
  if (wid >= N) return;
  int lane = threadIdx.x & 63;
  int g = lane >> 3;          // edge group 0..7
  int c8 = (lane & 7) * 8;    // column oct base
  int deg0 = cnt[wid];
  int deg = deg0 < ELLCAP ? deg0 : ELLCAP;
  const unsigned short* row = ell + ((size_t)wid << 6);

  float acc[8] = {0.f, 0.f, 0.f, 0.f, 0.f, 0.f, 0.f, 0.f};
  int j = g;
  for (; j + 8 < deg; j += 16) {
    int s0 = __builtin_nontemporal_load(&row[j]);
    int s1 = __builtin_nontemporal_load(&row[j + 8]);
    float d0 = dinv32[s0];
    float d1 = dinv32[s1];
    half8_t v0 = *(const half8_t*)(table + ((size_t)s0 << 6) + c8);
    half8_t v1 = *(const half8_t*)(table + ((size_t)s1 << 6) + c8);
#pragma unroll
    for (int k = 0; k < 8; ++k) acc[k] = fmaf(d0, (float)v0[k], fmaf(d1, (float)v1[k], acc[k]));
  }
  if (j < deg) {
    int s0 = __builtin_nontemporal_load(&row[j]);
    float d0 = dinv32[s0];
    half8_t v0 = *(const half8_t*)(table + ((size_t)s0 << 6) + c8);
#pragma unroll
    for (int k = 0; k < 8; ++k) acc[k] = fmaf(d0, (float)v0[k], acc[k]);
  }
#pragma unroll
  for (int k = 0; k < 8; ++k) {
    acc[k] += __shfl_xor(acc[k], 8);
    acc[k] += __shfl_xor(acc[k], 16);
    acc[k] += __shfl_xor(acc[k], 32);
  }
  if (g == 0) {
    float a = alpha * dinv32[wid];
    float r[8];
#pragma unroll
    for (int k = 0; k < 8; ++k) r[k] = a * acc[k];
    if (use_aux) {
      half8_t x = *(const half8_t*)(auxc + ((size_t)wid << 6) + c8);
#pragma unroll
      for (int k = 0; k < 8; ++k) r[k] -= (float)x[k];
    }
    half8_t ro;
#pragma unroll
    for (int k = 0; k < 8; ++k) ro[k] = (_Float16)r[k];
    *(half8_t*)(outc + ((size_t)wid << 6) + c8) = ro;
  }
}

// ---------------- conv1 linear: Y0c = relu([A0|A1|A2]@Wc1^T + bc1), compact in/out ----------------
__global__ __launch_bounds__(256) void k_gemm192(const _Float16* __restrict__ A0,
                                                 const _Float16* __restrict__ A1,
                                                 const _Float16* __restrict__ A2,
                                                 const _Float16* __restrict__ B,  // [64,192] fp16
                                                 const float* __restrict__ bias,
                                                 _Float16* __restrict__ outc, int N) {
  const int tid = threadIdx.x;
  const int wave = tid >> 6;
  const int lane = tid & 63;
  const int m = lane & 15;
  const int quad = lane >> 4;
  const int rbase = blockIdx.x * 64 + wave * 16;
  int arow = rbase + m;
  arow = arow < N ? arow : N - 1;
  const size_t ro = ((size_t)arow << 6) + quad * 8;
  const _Float16* Bp = B + (size_t)m * 192 + quad * 8;
  float4_t acc[4] = {{0.f,0.f,0.f,0.f},{0.f,0.f,0.f,0.f},{0.f,0.f,0.f,0.f},{0.f,0.f,0.f,0.f}};
#pragma unroll
  for (int k0 = 0; k0 < 192; k0 += 32) {
    half8_t a;
    if (k0 < 64) a = *(const half8_t*)(A0 + ro + k0);
    else if (k0 < 128) a = *(const half8_t*)(A1 + ro + (k0 - 64));
    else a = *(const half8_t*)(A2 + ro + (k0 - 128));
    half8_t b0 = *(const half8_t*)(Bp + k0);
    half8_t b1f = *(const half8_t*)(Bp + 16 * 192 + k0);
    half8_t b2f = *(const half8_t*)(Bp + 32 * 192 + k0);
    half8_t b3f = *(const half8_t*)(Bp + 48 * 192 + k0);
    acc[0] = __builtin_amdgcn_mfma_f32_16x16x32_f16(a, b0, acc[0], 0, 0, 0);
    acc[1] = __builtin_amdgcn_mfma_f32_16x16x32_f16(a, b1f, acc[1], 0, 0, 0);
    acc[2] = __builtin_amdgcn_mfma_f32_16x16x32_f16(a, b2f, acc[2], 0, 0, 0);
    acc[3] = __builtin_amdgcn_mfma_f32_16x16x32_f16(a, b3f, acc[3], 0, 0, 0);
  }
#pragma unroll
  for (int i = 0; i < 4; ++i) {
    int rr = rbase + quad * 4 + i;
    if (rr < N) {
#pragma unroll
      for (int t = 0; t < 4; ++t)
        outc[((size_t)rr << 6) + t * 16 + m] = (_Float16)fmaxf(acc[t][i] + bias[t * 16 + m], 0.f);
    }
  }
}

// ---------------- fused tail (row-local, NO gather): conv2-linear -> W3 -> head ----------------
__global__ __launch_bounds__(256) void k_tail(const _Float16* __restrict__ A0,
                                              const _Float16* __restrict__ A1,
                                              const _Float16* __restrict__ A2,
                                              const _Float16* __restrict__ w16,
                                              const float* __restrict__ bc2,
                                              const float* __restrict__ b3,
                                              const float* __restrict__ W4,
                                              const float* __restrict__ b4,
                                              float* __restrict__ out, int N) {
  __shared__ _Float16 Hs2[64][72];
  __shared__ float Hs3[64][65];
  const int tid = threadIdx.x;
  const int wave = tid >> 6;
  const int lane = tid & 63;
  const int m = lane & 15;
  const int quad = lane >> 4;
  const int rbase = blockIdx.x * 64 + wave * 16;
  int arow = rbase + m;
  arow = arow < N ? arow : N - 1;
  {
    const size_t ro = ((size_t)arow << 6) + quad * 8;
    const _Float16* Bp = w16 + WOFF_WC2 + (size_t)m * 192 + quad * 8;
    float4_t acc[4] = {{0.f,0.f,0.f,0.f},{0.f,0.f,0.f,0.f},{0.f,0.f,0.f,0.f},{0.f,0.f,0.f,0.f}};
#pragma unroll
    for (int k0 = 0; k0 < 192; k0 += 32) {
      half8_t a;
      if (k0 < 64) a = *(const half8_t*)(A0 + ro + k0);
      else if (k0 < 128) a = *(const half8_t*)(A1 + ro + (k0 - 64));
      else a = *(const half8_t*)(A2 + ro + (k0 - 128));
      half8_t b0 = *(const half8_t*)(Bp + k0);
      half8_t b1f = *(const half8_t*)(Bp + 16 * 192 + k0);
      half8_t b2f = *(const half8_t*)(Bp + 32 * 192 + k0);
      half8_t b3f = *(const half8_t*)(Bp + 48 * 192 + k0);
      acc[0] = __builtin_amdgcn_mfma_f32_16x16x32_f16(a, b0, acc[0], 0, 0, 0);
      acc[1] = __builtin_amdgcn_mfma_f32_16x16x32_f16(a, b1f, acc[1], 0, 0, 0);
      acc[2] = __builtin_amdgcn_mfma_f32_16x16x32_f16(a, b2f, acc[2], 0, 0, 0);
      acc[3] = __builtin_amdgcn_mfma_f32_16x16x32_f16(a, b3f, acc[3], 0, 0, 0);
    }
#pragma unroll
    for (int i = 0; i < 4; ++i)
#pragma unroll
      for (int t = 0; t < 4; ++t)
        Hs2[wave * 16 + quad * 4 + i][t * 16 + m] =
            (_Float16)fmaxf(acc[t][i] + bc2[t * 16 + m], 0.f);
  }
  __syncthreads();
  {
    const _Float16* Ap = &Hs2[wave * 16 + m][quad * 8];
    const _Float16* Bp = w16 + WOFF_W3 + (size_t)m * H + quad * 8;
    float4_t acc[4] = {{0.f,0.f,0.f,0.f},{0.f,0.f,0.f,0.f},{0.f,0.f,0.f,0.f},{0.f,0.f,0.f,0.f}};
#pragma unroll
    for (int k0 = 0; k0 < H; k0 += 32) {
      half8_t a = *(const half8_t*)(Ap + k0);
      half8_t b0 = *(const half8_t*)(Bp + k0);
      half8_t b1f = *(const half8_t*)(Bp + 16 * H + k0);
      half8_t b2f = *(const half8_t*)(Bp + 32 * H + k0);
      half8_t b3f = *(const half8_t*)(Bp + 48 * H + k0);
      acc[0] = __builtin_amdgcn_mfma_f32_16x16x32_f16(a, b0, acc[0], 0, 0, 0);
      acc[1] = __builtin_amdgcn_mfma_f32_16x16x32_f16(a, b1f, acc[1], 0, 0, 0);
      acc[2] = __builtin_amdgcn_mfma_f32_16x16x32_f16(a, b2f, acc[2], 0, 0, 0);
      acc[3] = __builtin_amdgcn_mfma_f32_16x16x32_f16(a, b3f, acc[3], 0, 0, 0);
    }
#pragma unroll
    for (int i = 0; i < 4; ++i)
#pragma unroll
      for (int t = 0; t < 4; ++t)
        Hs3[wave * 16 + quad * 4 + i][t * 16 + m] = fmaxf(acc[t][i] + b3[t * 16 + m], 0.f);
  }
  __syncthreads();
  if (tid < 128) {
    int r = tid >> 1;
    int c = tid & 1;
    int row = blockIdx.x * 64 + r;
    if (row < N) {
      const float* w4 = W4 + c * 64;
      float s = 0.f;
#pragma unroll
      for (int k = 0; k < 64; ++k) s = fmaf(Hs3[r][k], w4[k], s);
      out[(size_t)row * 2 + c] = s + b4[c];
    }
  }
}

extern "C" void kernel_launch(void* const* d_in, const int* in_sizes, int n_in,
                              void* d_out, int out_size, void* d_ws, size_t ws_size,
                              hipStream_t stream) {
  const float* in_feat = (const float*)d_in[0];
  const int* src = (const int*)d_in[1];
  const int* dst = (const int*)d_in[2];
  const float* W1 = (const float*)d_in[3];
  const float* b1 = (const float*)d_in[4];
  const float* W2 = (const float*)d_in[5];
  const float* b2 = (const float*)d_in[6];
  const float* Wc1 = (const float*)d_in[7];
  const float* bc1 = (const float*)d_in[8];
  const float* Wc2 = (const float*)d_in[9];
  const float* bc2 = (const float*)d_in[10];
  const float* W3 = (const float*)d_in[11];
  const float* b3 = (const float*)d_in[12];
  const float* W4 = (const float*)d_in[13];
  const float* b4 = (const float*)d_in[14];
  float* out = (float*)d_out;

  char* ws = (char*)d_ws;
  size_t o = 0;
  auto carve = [&](size_t bytes) -> void* {
    o = (o + 255) & ~(size_t)255;
    void* p = ws + o;
    o += bytes;
    return p;
  };
  int* cnt = (int*)carve((size_t)NN * 4);
  unsigned short* ell = (unsigned short*)carve((size_t)NN * ELLCAP * 2);  // 6.4 MB u16
  float* dinv32 = (float*)carve((size_t)NN * 4);
  _Float16* w16 = (_Float16*)carve((size_t)WTOT * 2);
  _Float16* X0c = (_Float16*)carve((size_t)NN * H * 2);   // conv1 X0 (unscaled)
  _Float16* X1c = (_Float16*)carve((size_t)NN * H * 2);   // conv1 X1
  _Float16* X2c = (_Float16*)carve((size_t)NN * H * 2);   // conv1 X2
  _Float16* Y0c = (_Float16*)carve((size_t)NN * H * 2);   // conv2 X0 (= conv1 out)
  _Float16* Y1c = (_Float16*)carve((size_t)NN * H * 2);
  _Float16* Y2c = (_Float16*)carve((size_t)NN * H * 2);
  (void)ws_size; (void)in_sizes; (void)n_in; (void)out_size;

  const int NB_W = (NN * 64 + 255) / 256;       // 12500
  const int NB_PREP = NB_FILL + NB_CVTW;        // 1020

  hipMemsetAsync(cnt, 0, (size_t)NN * 4, stream);
  // fillell(u16) + weight cvt
  k_prep<<<NB_PREP, 256, 0, stream>>>(src, dst, cnt, ell, W1, W2, Wc1, Wc2, W3, w16);
  // dinv32 build + entry MLP -> X0c
  k_mlp<<<NB_DINV + NB_G, 256, 0, stream>>>(in_feat, w16, b1, b2, cnt, dinv32, X0c, NN);
  // conv1: X1 = -A.X0
  k_spmm<<<NB_W, 256, 0, stream>>>(X0c, (const _Float16*)nullptr, X1c, cnt, dinv32, ell, -1.f, 0, NN);
  // conv1: X2 = -2*A.X1 - X0
  k_spmm<<<NB_W, 256, 0, stream>>>(X1c, X0c, X2c, cnt, dinv32, ell, -2.f, 1, NN);
  // conv1 linear -> Y0c
  k_gemm192<<<NB_G, 256, 0, stream>>>(X0c, X1c, X2c, w16 + WOFF_WC1, bc1, Y0c, NN);
  // conv2: Y1 = -A.Y0
  k_spmm<<<NB_W, 256, 0, stream>>>(Y0c, (const _Float16*)nullptr, Y1c, cnt, dinv32, ell, -1.f, 0, NN);
  // conv2: Y2 = -2*A.Y1 - Y0
  k_spmm<<<NB_W, 256, 0, stream>>>(Y1c, Y0c, Y2c, cnt, dinv32, ell, -2.f, 1, NN);
  // fused tail: conv2-linear -> W3 -> head
  k_tail<<<NB_G, 256, 0, stream>>>(Y0c, Y1c, Y2c, w16, bc2, b3, W4, b4, out, NN);
}

// Round 15
// 272.937 us; speedup vs baseline: 1.4456x; 1.1211x over previous
//
#include <hip/hip_runtime.h>
#include <hip/hip_fp16.h>
#include <math.h>

#define NN 50000
#define NE 800000
#define INF 128
#define H 64
#define ELLCAP 64
#define NPART 8
#define PSIZE ((NN + NPART - 1) / NPART)  // 6250
#define EPT 25                            // edges per thread per chunk
#define CHUNK (256 * EPT)                 // 6400
#define NCHUNK ((NE + CHUNK - 1) / CHUNK) // 125
#define NB_FILL (NCHUNK * NPART)          // 1000
#define NB_G ((NN + 63) / 64)             // 782
// packed fp16 weights: W1|W2|Wc1|Wc2|W3
#define WOFF_W1 0
#define WOFF_W2 8192
#define WOFF_WC1 12288
#define WOFF_WC2 24576
#define WOFF_W3 36864
#define WTOT 40960
#define NB_CVTW (WTOT / 2048)             // 20
#define NB_DINV 25                        // 25*2048 >= 50000

typedef _Float16 half8_t __attribute__((ext_vector_type(8)));
typedef float float4_t __attribute__((ext_vector_type(4)));

__device__ __forceinline__ half8_t load_cvt8(const float* p) {
  float4 a = *(const float4*)(p);
  float4 b = *(const float4*)(p + 4);
  half8_t h;
  h[0] = (_Float16)a.x; h[1] = (_Float16)a.y; h[2] = (_Float16)a.z; h[3] = (_Float16)a.w;
  h[4] = (_Float16)b.x; h[5] = (_Float16)b.y; h[6] = (_Float16)b.z; h[7] = (_Float16)b.w;
  return h;
}

// ---------------- prep: fillell(u16) + weight-cvt ----------------
// Plateau (R1-R5): scattered-atomic edge pass pinned at ~19 atomics/ns (~52 us).
// R9/R10: do NOT co-schedule memory-heavy work with it. R12/R13: don't split it.
__global__ __launch_bounds__(256) void k_prep(const int* __restrict__ src, const int* __restrict__ dst,
                                              int* __restrict__ cnt, unsigned short* __restrict__ ell,
                                              const float* __restrict__ W1, const float* __restrict__ W2,
                                              const float* __restrict__ Wc1, const float* __restrict__ Wc2,
                                              const float* __restrict__ W3, _Float16* __restrict__ w16) {
  int b = blockIdx.x;
  if (b < NB_FILL) {
    int p = b & (NPART - 1);
    int chunk = b >> 3;
    int lo = p * PSIZE, hi = lo + PSIZE;
    int base = chunk * CHUNK + threadIdx.x;
#pragma unroll
    for (int i = 0; i < EPT; ++i) {
      int e = base + i * 256;
      if (e < NE) {
        int d = __builtin_nontemporal_load(&dst[e]);
        if (d >= lo && d < hi) {
          int s = __builtin_nontemporal_load(&src[e]);
          int c = atomicAdd(&cnt[d], 1);
          if (c < ELLCAP) ell[((size_t)d << 6) + c] = (unsigned short)s;  // ids < 65536
        }
      }
    }
  } else {
    int i0 = (b - NB_FILL) * 2048 + threadIdx.x * 8;
#pragma unroll
    for (int k = 0; k < 8; ++k) {
      int id = i0 + k;
      if (id < WTOT) {
        float v;
        if (id < WOFF_W2) v = W1[id];
        else if (id < WOFF_WC1) v = W2[id - WOFF_W2];
        else if (id < WOFF_WC2) v = Wc1[id - WOFF_WC1];
        else if (id < WOFF_W3) v = Wc2[id - WOFF_WC2];
        else v = W3[id - WOFF_W3];
        w16[id] = (_Float16)v;
      }
    }
  }
}

// ---------------- mlp (+ dinv32 build in leading blocks) ----------------
__global__ __launch_bounds__(256) void k_mlp(const float* __restrict__ in_feat,
                                             const _Float16* __restrict__ w16,
                                             const float* __restrict__ b1,
                                             const float* __restrict__ b2,
                                             const int* __restrict__ cnt,
                                             float* __restrict__ dinv32,
                                             _Float16* __restrict__ X0c, int N) {
  __shared__ _Float16 Hs[64][72];
  if (blockIdx.x < NB_DINV) {
    int i0 = blockIdx.x * 2048 + threadIdx.x * 8;
#pragma unroll
    for (int k = 0; k < 8; ++k) {
      int i = i0 + k;
      if (i < N) {
        int c = cnt[i];
        dinv32[i] = 1.0f / sqrtf((float)(c < 1 ? 1 : c));
      }
    }
    return;
  }
  const int tid = threadIdx.x;
  const int wave = tid >> 6;
  const int lane = tid & 63;
  const int m = lane & 15;
  const int quad = lane >> 4;
  const int rbase = (blockIdx.x - NB_DINV) * 64 + wave * 16;
  int arow = rbase + m;
  arow = arow < N ? arow : N - 1;
  const float* Ap = in_feat + (size_t)arow * INF + quad * 8;
  const _Float16* B1 = w16 + WOFF_W1 + (size_t)m * INF + quad * 8;
  float4_t acc[4] = {{0.f,0.f,0.f,0.f},{0.f,0.f,0.f,0.f},{0.f,0.f,0.f,0.f},{0.f,0.f,0.f,0.f}};
#pragma unroll
  for (int k0 = 0; k0 < INF; k0 += 32) {
    half8_t a = load_cvt8(Ap + k0);
    half8_t b0 = *(const half8_t*)(B1 + k0);
    half8_t b1f = *(const half8_t*)(B1 + 16 * INF + k0);
    half8_t b2f = *(const half8_t*)(B1 + 32 * INF + k0);
    half8_t b3f = *(const half8_t*)(B1 + 48 * INF + k0);
    acc[0] = __builtin_amdgcn_mfma_f32_16x16x32_f16(a, b0, acc[0], 0, 0, 0);
    acc[1] = __builtin_amdgcn_mfma_f32_16x16x32_f16(a, b1f, acc[1], 0, 0, 0);
    acc[2] = __builtin_amdgcn_mfma_f32_16x16x32_f16(a, b2f, acc[2], 0, 0, 0);
    acc[3] = __builtin_amdgcn_mfma_f32_16x16x32_f16(a, b3f, acc[3], 0, 0, 0);
  }
#pragma unroll
  for (int i = 0; i < 4; ++i)
#pragma unroll
    for (int t = 0; t < 4; ++t)
      Hs[wave * 16 + quad * 4 + i][t * 16 + m] = (_Float16)fmaxf(acc[t][i] + b1[t * 16 + m], 0.f);
  __syncthreads();
  const _Float16* Ap2 = &Hs[wave * 16 + m][quad * 8];
  const _Float16* B2 = w16 + WOFF_W2 + (size_t)m * H + quad * 8;
  float4_t acc2[4] = {{0.f,0.f,0.f,0.f},{0.f,0.f,0.f,0.f},{0.f,0.f,0.f,0.f},{0.f,0.f,0.f,0.f}};
#pragma unroll
  for (int k0 = 0; k0 < H; k0 += 32) {
    half8_t a = *(const half8_t*)(Ap2 + k0);
    half8_t b0 = *(const half8_t*)(B2 + k0);
    half8_t b1f = *(const half8_t*)(B2 + 16 * H + k0);
    half8_t b2f = *(const half8_t*)(B2 + 32 * H + k0);
    half8_t b3f = *(const half8_t*)(B2 + 48 * H + k0);
    acc2[0] = __builtin_amdgcn_mfma_f32_16x16x32_f16(a, b0, acc2[0], 0, 0, 0);
    acc2[1] = __builtin_amdgcn_mfma_f32_16x16x32_f16(a, b1f, acc2[1], 0, 0, 0);
    acc2[2] = __builtin_amdgcn_mfma_f32_16x16x32_f16(a, b2f, acc2[2], 0, 0, 0);
    acc2[3] = __builtin_amdgcn_mfma_f32_16x16x32_f16(a, b3f, acc2[3], 0, 0, 0);
  }
#pragma unroll
  for (int i = 0; i < 4; ++i) {
    int rr = rbase + quad * 4 + i;
    if (rr < N) {
#pragma unroll
      for (int t = 0; t < 4; ++t)
        X0c[((size_t)rr << 6) + t * 16 + m] = (_Float16)fmaxf(acc2[t][i] + b2[t * 16 + m], 0.f);
    }
  }
}

// ---------------- SpMM: TWO nodes per wave, 4 gathers in flight ----------------
// R14 lesson: spmm is gather-LATENCY-bound (FETCH 58MB at 18% HBM BW, VALU work
// ~3us aggregate). Lever = memory-level parallelism. Lanes 0-31 -> node 2w,
// lanes 32-63 -> node 2w+1; per half: 4 edge-groups x 8 col-octs (16B loads).
// Dual-unroll -> 4 independent gathers in flight per wave (vs 2 before).
// Reduce: xor 8,16 within each 32-half (2 rounds vs 3). No nt on index loads
// (R14 suspect). outc[n] = alpha*dinv32[n]*sum_s dinv32[s]*table[s] (- auxc[n]).
__global__ __launch_bounds__(256) void k_spmm(const _Float16* __restrict__ table,
                                              const _Float16* __restrict__ auxc,
                                              _Float16* __restrict__ outc,
                                              const int* __restrict__ cnt,
                                              const float* __restrict__ dinv32,
                                              const unsigned short* __restrict__ ell,
                                              float alpha, int use_aux, int N) {
  int wv = (blockIdx.x * 256 + threadIdx.x) >> 6;
  int lane = threadIdx.x & 63;
  int node = wv * 2 + (lane >> 5);
  if (node >= N) return;
  int g = (lane >> 3) & 3;    // edge group 0..3 within this node's half
  int c8 = (lane & 7) * 8;    // column oct base
  int deg0 = cnt[node];
  int deg = deg0 < ELLCAP ? deg0 : ELLCAP;
  const unsigned short* row = ell + ((size_t)node << 6);

  float acc[8] = {0.f, 0.f, 0.f, 0.f, 0.f, 0.f, 0.f, 0.f};
  int j = g;
  for (; j + 4 < deg; j += 8) {
    int s0 = row[j];
    int s1 = row[j + 4];
    float d0 = dinv32[s0];
    float d1 = dinv32[s1];
    half8_t v0 = *(const half8_t*)(table + ((size_t)s0 << 6) + c8);
    half8_t v1 = *(const half8_t*)(table + ((size_t)s1 << 6) + c8);
#pragma unroll
    for (int k = 0; k < 8; ++k) acc[k] = fmaf(d0, (float)v0[k], fmaf(d1, (float)v1[k], acc[k]));
  }
  if (j < deg) {
    int s0 = row[j];
    float d0 = dinv32[s0];
    half8_t v0 = *(const half8_t*)(table + ((size_t)s0 << 6) + c8);
#pragma unroll
    for (int k = 0; k < 8; ++k) acc[k] = fmaf(d0, (float)v0[k], acc[k]);
  }
  // reduce across the 4 edge groups of this half (xor 8, 16 stay within the half)
#pragma unroll
  for (int k = 0; k < 8; ++k) {
    acc[k] += __shfl_xor(acc[k], 8);
    acc[k] += __shfl_xor(acc[k], 16);
  }
  if (g == 0) {
    float a = alpha * dinv32[node];
    float r[8];
#pragma unroll
    for (int k = 0; k < 8; ++k) r[k] = a * acc[k];
    if (use_aux) {
      half8_t x = *(const half8_t*)(auxc + ((size_t)node << 6) + c8);
#pragma unroll
      for (int k = 0; k < 8; ++k) r[k] -= (float)x[k];
    }
    half8_t ro;
#pragma unroll
    for (int k = 0; k < 8; ++k) ro[k] = (_Float16)r[k];
    *(half8_t*)(outc + ((size_t)node << 6) + c8) = ro;
  }
}

// ---------------- conv1 linear: Y0c = relu([A0|A1|A2]@Wc1^T + bc1), compact in/out ----------------
__global__ __launch_bounds__(256) void k_gemm192(const _Float16* __restrict__ A0,
                                                 const _Float16* __restrict__ A1,
                                                 const _Float16* __restrict__ A2,
                                                 const _Float16* __restrict__ B,  // [64,192] fp16
                                                 const float* __restrict__ bias,
                                                 _Float16* __restrict__ outc, int N) {
  const int tid = threadIdx.x;
  const int wave = tid >> 6;
  const int lane = tid & 63;
  const int m = lane & 15;
  const int quad = lane >> 4;
  const int rbase = blockIdx.x * 64 + wave * 16;
  int arow = rbase + m;
  arow = arow < N ? arow : N - 1;
  const size_t ro = ((size_t)arow << 6) + quad * 8;
  const _Float16* Bp = B + (size_t)m * 192 + quad * 8;
  float4_t acc[4] = {{0.f,0.f,0.f,0.f},{0.f,0.f,0.f,0.f},{0.f,0.f,0.f,0.f},{0.f,0.f,0.f,0.f}};
#pragma unroll
  for (int k0 = 0; k0 < 192; k0 += 32) {
    half8_t a;
    if (k0 < 64) a = *(const half8_t*)(A0 + ro + k0);
    else if (k0 < 128) a = *(const half8_t*)(A1 + ro + (k0 - 64));
    else a = *(const half8_t*)(A2 + ro + (k0 - 128));
    half8_t b0 = *(const half8_t*)(Bp + k0);
    half8_t b1f = *(const half8_t*)(Bp + 16 * 192 + k0);
    half8_t b2f = *(const half8_t*)(Bp + 32 * 192 + k0);
    half8_t b3f = *(const half8_t*)(Bp + 48 * 192 + k0);
    acc[0] = __builtin_amdgcn_mfma_f32_16x16x32_f16(a, b0, acc[0], 0, 0, 0);
    acc[1] = __builtin_amdgcn_mfma_f32_16x16x32_f16(a, b1f, acc[1], 0, 0, 0);
    acc[2] = __builtin_amdgcn_mfma_f32_16x16x32_f16(a, b2f, acc[2], 0, 0, 0);
    acc[3] = __builtin_amdgcn_mfma_f32_16x16x32_f16(a, b3f, acc[3], 0, 0, 0);
  }
#pragma unroll
  for (int i = 0; i < 4; ++i) {
    int rr = rbase + quad * 4 + i;
    if (rr < N) {
#pragma unroll
      for (int t = 0; t < 4; ++t)
        outc[((size_t)rr << 6) + t * 16 + m] = (_Float16)fmaxf(acc[t][i] + bias[t * 16 + m], 0.f);
    }
  }
}

// ---------------- fused tail (row-local, NO gather): conv2-linear -> W3 -> head ----------------
__global__ __launch_bounds__(256) void k_tail(const _Float16* __restrict__ A0,
                                              const _Float16* __restrict__ A1,
                                              const _Float16* __restrict__ A2,
                                              const _Float16* __restrict__ w16,
                                              const float* __restrict__ bc2,
                                              const float* __restrict__ b3,
                                              const float* __restrict__ W4,
                                              const float* __restrict__ b4,
                                              float* __restrict__ out, int N) {
  __shared__ _Float16 Hs2[64][72];
  __shared__ float Hs3[64][65];
  const int tid = threadIdx.x;
  const int wave = tid >> 6;
  const int lane = tid & 63;
  const int m = lane & 15;
  const int quad = lane >> 4;
  const int rbase = blockIdx.x * 64 + wave * 16;
  int arow = rbase + m;
  arow = arow < N ? arow : N - 1;
  {
    const size_t ro = ((size_t)arow << 6) + quad * 8;
    const _Float16* Bp = w16 + WOFF_WC2 + (size_t)m * 192 + quad * 8;
    float4_t acc[4] = {{0.f,0.f,0.f,0.f},{0.f,0.f,0.f,0.f},{0.f,0.f,0.f,0.f},{0.f,0.f,0.f,0.f}};
#pragma unroll
    for (int k0 = 0; k0 < 192; k0 += 32) {
      half8_t a;
      if (k0 < 64) a = *(const half8_t*)(A0 + ro + k0);
      else if (k0 < 128) a = *(const half8_t*)(A1 + ro + (k0 - 64));
      else a = *(const half8_t*)(A2 + ro + (k0 - 128));
      half8_t b0 = *(const half8_t*)(Bp + k0);
      half8_t b1f = *(const half8_t*)(Bp + 16 * 192 + k0);
      half8_t b2f = *(const half8_t*)(Bp + 32 * 192 + k0);
      half8_t b3f = *(const half8_t*)(Bp + 48 * 192 + k0);
      acc[0] = __builtin_amdgcn_mfma_f32_16x16x32_f16(a, b0, acc[0], 0, 0, 0);
      acc[1] = __builtin_amdgcn_mfma_f32_16x16x32_f16(a, b1f, acc[1], 0, 0, 0);
      acc[2] = __builtin_amdgcn_mfma_f32_16x16x32_f16(a, b2f, acc[2], 0, 0, 0);
      acc[3] = __builtin_amdgcn_mfma_f32_16x16x32_f16(a, b3f, acc[3], 0, 0, 0);
    }
#pragma unroll
    for (int i = 0; i < 4; ++i)
#pragma unroll
      for (int t = 0; t < 4; ++t)
        Hs2[wave * 16 + quad * 4 + i][t * 16 + m] =
            (_Float16)fmaxf(acc[t][i] + bc2[t * 16 + m], 0.f);
  }
  __syncthreads();
  {
    const _Float16* Ap = &Hs2[wave * 16 + m][quad * 8];
    const _Float16* Bp = w16 + WOFF_W3 + (size_t)m * H + quad * 8;
    float4_t acc[4] = {{0.f,0.f,0.f,0.f},{0.f,0.f,0.f,0.f},{0.f,0.f,0.f,0.f},{0.f,0.f,0.f,0.f}};
#pragma unroll
    for (int k0 = 0; k0 < H; k0 += 32) {
      half8_t a = *(const half8_t*)(Ap + k0);
      half8_t b0 = *(const half8_t*)(Bp + k0);
      half8_t b1f = *(const half8_t*)(Bp + 16 * H + k0);
      half8_t b2f = *(const half8_t*)(Bp + 32 * H + k0);
      half8_t b3f = *(const half8_t*)(Bp + 48 * H + k0);
      acc[0] = __builtin_amdgcn_mfma_f32_16x16x32_f16(a, b0, acc[0], 0, 0, 0);
      acc[1] = __builtin_amdgcn_mfma_f32_16x16x32_f16(a, b1f, acc[1], 0, 0, 0);
      acc[2] = __builtin_amdgcn_mfma_f32_16x16x32_f16(a, b2f, acc[2], 0, 0, 0);
      acc[3] = __builtin_amdgcn_mfma_f32_16x16x32_f16(a, b3f, acc[3], 0, 0, 0);
    }
#pragma unroll
    for (int i = 0; i < 4; ++i)
#pragma unroll
      for (int t = 0; t < 4; ++t)
        Hs3[wave * 16 + quad * 4 + i][t * 16 + m] = fmaxf(acc[t][i] + b3[t * 16 + m], 0.f);
  }
  __syncthreads();
  if (tid < 128) {
    int r = tid >> 1;
    int c = tid & 1;
    int row = blockIdx.x * 64 + r;
    if (row < N) {
      const float* w4 = W4 + c * 64;
      float s = 0.f;
#pragma unroll
      for (int k = 0; k < 64; ++k) s = fmaf(Hs3[r][k], w4[k], s);
      out[(size_t)row * 2 + c] = s + b4[c];
    }
  }
}

extern "C" void kernel_launch(void* const* d_in, const int* in_sizes, int n_in,
                              void* d_out, int out_size, void* d_ws, size_t ws_size,
                              hipStream_t stream) {
  const float* in_feat = (const float*)d_in[0];
  const int* src = (const int*)d_in[1];
  const int* dst = (const int*)d_in[2];
  const float* W1 = (const float*)d_in[3];
  const float* b1 = (const float*)d_in[4];
  const float* W2 = (const float*)d_in[5];
  const float* b2 = (const float*)d_in[6];
  const float* Wc1 = (const float*)d_in[7];
  const float* bc1 = (const float*)d_in[8];
  const float* Wc2 = (const float*)d_in[9];
  const float* bc2 = (const float*)d_in[10];
  const float* W3 = (const float*)d_in[11];
  const float* b3 = (const float*)d_in[12];
  const float* W4 = (const float*)d_in[13];
  const float* b4 = (const float*)d_in[14];
  float* out = (float*)d_out;

  char* ws = (char*)d_ws;
  size_t o = 0;
  auto carve = [&](size_t bytes) -> void* {
    o = (o + 255) & ~(size_t)255;
    void* p = ws + o;
    o += bytes;
    return p;
  };
  int* cnt = (int*)carve((size_t)NN * 4);
  unsigned short* ell = (unsigned short*)carve((size_t)NN * ELLCAP * 2);  // 6.4 MB u16
  float* dinv32 = (float*)carve((size_t)NN * 4);
  _Float16* w16 = (_Float16*)carve((size_t)WTOT * 2);
  _Float16* X0c = (_Float16*)carve((size_t)NN * H * 2);   // conv1 X0 (unscaled)
  _Float16* X1c = (_Float16*)carve((size_t)NN * H * 2);   // conv1 X1
  _Float16* X2c = (_Float16*)carve((size_t)NN * H * 2);   // conv1 X2
  _Float16* Y0c = (_Float16*)carve((size_t)NN * H * 2);   // conv2 X0 (= conv1 out)
  _Float16* Y1c = (_Float16*)carve((size_t)NN * H * 2);
  _Float16* Y2c = (_Float16*)carve((size_t)NN * H * 2);
  (void)ws_size; (void)in_sizes; (void)n_in; (void)out_size;

  const int NB_W2 = ((NN + 1) / 2 * 64 + 255) / 256;  // 6250: 2 nodes/wave
  const int NB_PREP = NB_FILL + NB_CVTW;              // 1020

  hipMemsetAsync(cnt, 0, (size_t)NN * 4, stream);
  // fillell(u16) + weight cvt
  k_prep<<<NB_PREP, 256, 0, stream>>>(src, dst, cnt, ell, W1, W2, Wc1, Wc2, W3, w16);
  // dinv32 build + entry MLP -> X0c
  k_mlp<<<NB_DINV + NB_G, 256, 0, stream>>>(in_feat, w16, b1, b2, cnt, dinv32, X0c, NN);
  // conv1: X1 = -A.X0
  k_spmm<<<NB_W2, 256, 0, stream>>>(X0c, (const _Float16*)nullptr, X1c, cnt, dinv32, ell, -1.f, 0, NN);
  // conv1: X2 = -2*A.X1 - X0
  k_spmm<<<NB_W2, 256, 0, stream>>>(X1c, X0c, X2c, cnt, dinv32, ell, -2.f, 1, NN);
  // conv1 linear -> Y0c
  k_gemm192<<<NB_G, 256, 0, stream>>>(X0c, X1c, X2c, w16 + WOFF_WC1, bc1, Y0c, NN);
  // conv2: Y1 = -A.Y0
  k_spmm<<<NB_W2, 256, 0, stream>>>(Y0c, (const _Float16*)nullptr, Y1c, cnt, dinv32, ell, -1.f, 0, NN);
  // conv2: Y2 = -2*A.Y1 - Y0
  k_spmm<<<NB_W2, 256, 0, stream>>>(Y1c, Y0c, Y2c, cnt, dinv32, ell, -2.f, 1, NN);
  // fused tail: conv2-linear -> W3 -> head
  k_tail<<<NB_G, 256, 0, stream>>>(Y0c, Y1c, Y2c, w16, bc2, b3, W4, b4, out, NN);
}

// Round 16
// 267.426 us; speedup vs baseline: 1.4753x; 1.0206x over previous
//
#include <hip/hip_runtime.h>
#include <hip/hip_fp16.h>
#include <math.h>

#define NN 50000
#define NE 800000
#define INF 128
#define H 64
#define ELLCAP 64
#define NPART 8
#define PSIZE ((NN + NPART - 1) / NPART)  // 6250
#define EPT 25                            // edges per thread per chunk
#define CHUNK (256 * EPT)                 // 6400
#define NCHUNK ((NE + CHUNK - 1) / CHUNK) // 125
#define NB_FILL (NCHUNK * NPART)          // 1000
#define NB_G ((NN + 63) / 64)             // 782
// packed fp16 weights: W1|W2|Wc1|Wc2|W3
#define WOFF_W1 0
#define WOFF_W2 8192
#define WOFF_WC1 12288
#define WOFF_WC2 24576
#define WOFF_W3 36864
#define WTOT 40960
#define NB_CVTW (WTOT / 2048)             // 20
#define NB_DINV 25                        // 25*2048 >= 50000

typedef _Float16 half8_t __attribute__((ext_vector_type(8)));
typedef float float4_t __attribute__((ext_vector_type(4)));

__device__ __forceinline__ half8_t load_cvt8(const float* p) {
  float4 a = *(const float4*)(p);
  float4 b = *(const float4*)(p + 4);
  half8_t h;
  h[0] = (_Float16)a.x; h[1] = (_Float16)a.y; h[2] = (_Float16)a.z; h[3] = (_Float16)a.w;
  h[4] = (_Float16)b.x; h[5] = (_Float16)b.y; h[6] = (_Float16)b.z; h[7] = (_Float16)b.w;
  return h;
}

// ---------------- prep: fillell(u16) + weight-cvt ----------------
// Plateau (R1-R5): scattered-atomic edge pass pinned at ~19 atomics/ns (~51 us).
// R9/R10: do NOT co-schedule memory-heavy work with it. R12/R13: don't split it.
__global__ __launch_bounds__(256) void k_prep(const int* __restrict__ src, const int* __restrict__ dst,
                                              int* __restrict__ cnt, unsigned short* __restrict__ ell,
                                              const float* __restrict__ W1, const float* __restrict__ W2,
                                              const float* __restrict__ Wc1, const float* __restrict__ Wc2,
                                              const float* __restrict__ W3, _Float16* __restrict__ w16) {
  int b = blockIdx.x;
  if (b < NB_FILL) {
    int p = b & (NPART - 1);
    int chunk = b >> 3;
    int lo = p * PSIZE, hi = lo + PSIZE;
    int base = chunk * CHUNK + threadIdx.x;
#pragma unroll
    for (int i = 0; i < EPT; ++i) {
      int e = base + i * 256;
      if (e < NE) {
        int d = __builtin_nontemporal_load(&dst[e]);
        if (d >= lo && d < hi) {
          int s = __builtin_nontemporal_load(&src[e]);
          int c = atomicAdd(&cnt[d], 1);
          if (c < ELLCAP) ell[((size_t)d << 6) + c] = (unsigned short)s;  // ids < 65536
        }
      }
    }
  } else {
    int i0 = (b - NB_FILL) * 2048 + threadIdx.x * 8;
#pragma unroll
    for (int k = 0; k < 8; ++k) {
      int id = i0 + k;
      if (id < WTOT) {
        float v;
        if (id < WOFF_W2) v = W1[id];
        else if (id < WOFF_WC1) v = W2[id - WOFF_W2];
        else if (id < WOFF_WC2) v = Wc1[id - WOFF_WC1];
        else if (id < WOFF_W3) v = Wc2[id - WOFF_WC2];
        else v = W3[id - WOFF_W3];
        w16[id] = (_Float16)v;
      }
    }
  }
}

// ---------------- mlp (+ dinv32 build in leading blocks) ----------------
__global__ __launch_bounds__(256) void k_mlp(const float* __restrict__ in_feat,
                                             const _Float16* __restrict__ w16,
                                             const float* __restrict__ b1,
                                             const float* __restrict__ b2,
                                             const int* __restrict__ cnt,
                                             float* __restrict__ dinv32,
                                             _Float16* __restrict__ X0c, int N) {
  __shared__ _Float16 Hs[64][72];
  if (blockIdx.x < NB_DINV) {
    int i0 = blockIdx.x * 2048 + threadIdx.x * 8;
#pragma unroll
    for (int k = 0; k < 8; ++k) {
      int i = i0 + k;
      if (i < N) {
        int c = cnt[i];
        dinv32[i] = 1.0f / sqrtf((float)(c < 1 ? 1 : c));
      }
    }
    return;
  }
  const int tid = threadIdx.x;
  const int wave = tid >> 6;
  const int lane = tid & 63;
  const int m = lane & 15;
  const int quad = lane >> 4;
  const int rbase = (blockIdx.x - NB_DINV) * 64 + wave * 16;
  int arow = rbase + m;
  arow = arow < N ? arow : N - 1;
  const float* Ap = in_feat + (size_t)arow * INF + quad * 8;
  const _Float16* B1 = w16 + WOFF_W1 + (size_t)m * INF + quad * 8;
  float4_t acc[4] = {{0.f,0.f,0.f,0.f},{0.f,0.f,0.f,0.f},{0.f,0.f,0.f,0.f},{0.f,0.f,0.f,0.f}};
#pragma unroll
  for (int k0 = 0; k0 < INF; k0 += 32) {
    half8_t a = load_cvt8(Ap + k0);
    half8_t b0 = *(const half8_t*)(B1 + k0);
    half8_t b1f = *(const half8_t*)(B1 + 16 * INF + k0);
    half8_t b2f = *(const half8_t*)(B1 + 32 * INF + k0);
    half8_t b3f = *(const half8_t*)(B1 + 48 * INF + k0);
    acc[0] = __builtin_amdgcn_mfma_f32_16x16x32_f16(a, b0, acc[0], 0, 0, 0);
    acc[1] = __builtin_amdgcn_mfma_f32_16x16x32_f16(a, b1f, acc[1], 0, 0, 0);
    acc[2] = __builtin_amdgcn_mfma_f32_16x16x32_f16(a, b2f, acc[2], 0, 0, 0);
    acc[3] = __builtin_amdgcn_mfma_f32_16x16x32_f16(a, b3f, acc[3], 0, 0, 0);
  }
#pragma unroll
  for (int i = 0; i < 4; ++i)
#pragma unroll
    for (int t = 0; t < 4; ++t)
      Hs[wave * 16 + quad * 4 + i][t * 16 + m] = (_Float16)fmaxf(acc[t][i] + b1[t * 16 + m], 0.f);
  __syncthreads();
  const _Float16* Ap2 = &Hs[wave * 16 + m][quad * 8];
  const _Float16* B2 = w16 + WOFF_W2 + (size_t)m * H + quad * 8;
  float4_t acc2[4] = {{0.f,0.f,0.f,0.f},{0.f,0.f,0.f,0.f},{0.f,0.f,0.f,0.f},{0.f,0.f,0.f,0.f}};
#pragma unroll
  for (int k0 = 0; k0 < H; k0 += 32) {
    half8_t a = *(const half8_t*)(Ap2 + k0);
    half8_t b0 = *(const half8_t*)(B2 + k0);
    half8_t b1f = *(const half8_t*)(B2 + 16 * H + k0);
    half8_t b2f = *(const half8_t*)(B2 + 32 * H + k0);
    half8_t b3f = *(const half8_t*)(B2 + 48 * H + k0);
    acc2[0] = __builtin_amdgcn_mfma_f32_16x16x32_f16(a, b0, acc2[0], 0, 0, 0);
    acc2[1] = __builtin_amdgcn_mfma_f32_16x16x32_f16(a, b1f, acc2[1], 0, 0, 0);
    acc2[2] = __builtin_amdgcn_mfma_f32_16x16x32_f16(a, b2f, acc2[2], 0, 0, 0);
    acc2[3] = __builtin_amdgcn_mfma_f32_16x16x32_f16(a, b3f, acc2[3], 0, 0, 0);
  }
#pragma unroll
  for (int i = 0; i < 4; ++i) {
    int rr = rbase + quad * 4 + i;
    if (rr < N) {
#pragma unroll
      for (int t = 0; t < 4; ++t)
        X0c[((size_t)rr << 6) + t * 16 + m] = (_Float16)fmaxf(acc2[t][i] + b2[t * 16 + m], 0.f);
    }
  }
}

// ---------------- SpMM: FOUR nodes per wave, 8 gathers in flight ----------------
// R14/R15 lessons: spmm is gather-latency-bound; the lever is outstanding
// gathers per resident wave (R15: 2 nodes/wave, 4 in flight, -20%). Now:
// lane>>4 -> node 4w+sub; per 16-lane group: 2 edge-groups x 8 col-octs
// (16B loads). Dual-unroll -> 8 independent gathers in flight per wave.
// Reduce: single xor 8. dinv32 (200 KB, L2-hot) for per-edge scale.
// outc[n] = alpha*dinv32[n]*sum_s dinv32[s]*table[s] (- auxc[n] if use_aux).
__global__ __launch_bounds__(256) void k_spmm(const _Float16* __restrict__ table,
                                              const _Float16* __restrict__ auxc,
                                              _Float16* __restrict__ outc,
                                              const int* __restrict__ cnt,
                                              const float* __restrict__ dinv32,
                                              const unsigned short* __restrict__ ell,
                                              float alpha, int use_aux, int N) {
  int wv = (blockIdx.x * 256 + threadIdx.x) >> 6;
  int lane = threadIdx.x & 63;
  int node = wv * 4 + (lane >> 4);
  if (node >= N) return;
  int g = (lane >> 3) & 1;    // edge group 0..1 within this node's 16-lane group
  int c8 = (lane & 7) * 8;    // column oct base
  int deg0 = cnt[node];
  int deg = deg0 < ELLCAP ? deg0 : ELLCAP;
  const unsigned short* row = ell + ((size_t)node << 6);

  float acc[8] = {0.f, 0.f, 0.f, 0.f, 0.f, 0.f, 0.f, 0.f};
  int j = g;
  for (; j + 2 < deg; j += 4) {
    int s0 = row[j];
    int s1 = row[j + 2];
    float d0 = dinv32[s0];
    float d1 = dinv32[s1];
    half8_t v0 = *(const half8_t*)(table + ((size_t)s0 << 6) + c8);
    half8_t v1 = *(const half8_t*)(table + ((size_t)s1 << 6) + c8);
#pragma unroll
    for (int k = 0; k < 8; ++k) acc[k] = fmaf(d0, (float)v0[k], fmaf(d1, (float)v1[k], acc[k]));
  }
  if (j < deg) {
    int s0 = row[j];
    float d0 = dinv32[s0];
    half8_t v0 = *(const half8_t*)(table + ((size_t)s0 << 6) + c8);
#pragma unroll
    for (int k = 0; k < 8; ++k) acc[k] = fmaf(d0, (float)v0[k], acc[k]);
  }
  // reduce across the 2 edge groups (xor 8 stays within the 16-lane group)
#pragma unroll
  for (int k = 0; k < 8; ++k) acc[k] += __shfl_xor(acc[k], 8);
  if (g == 0) {
    float a = alpha * dinv32[node];
    float r[8];
#pragma unroll
    for (int k = 0; k < 8; ++k) r[k] = a * acc[k];
    if (use_aux) {
      half8_t x = *(const half8_t*)(auxc + ((size_t)node << 6) + c8);
#pragma unroll
      for (int k = 0; k < 8; ++k) r[k] -= (float)x[k];
    }
    half8_t ro;
#pragma unroll
    for (int k = 0; k < 8; ++k) ro[k] = (_Float16)r[k];
    *(half8_t*)(outc + ((size_t)node << 6) + c8) = ro;
  }
}

// ---------------- conv1 linear: Y0c = relu([A0|A1|A2]@Wc1^T + bc1), compact in/out ----------------
__global__ __launch_bounds__(256) void k_gemm192(const _Float16* __restrict__ A0,
                                                 const _Float16* __restrict__ A1,
                                                 const _Float16* __restrict__ A2,
                                                 const _Float16* __restrict__ B,  // [64,192] fp16
                                                 const float* __restrict__ bias,
                                                 _Float16* __restrict__ outc, int N) {
  const int tid = threadIdx.x;
  const int wave = tid >> 6;
  const int lane = tid & 63;
  const int m = lane & 15;
  const int quad = lane >> 4;
  const int rbase = blockIdx.x * 64 + wave * 16;
  int arow = rbase + m;
  arow = arow < N ? arow : N - 1;
  const size_t ro = ((size_t)arow << 6) + quad * 8;
  const _Float16* Bp = B + (size_t)m * 192 + quad * 8;
  float4_t acc[4] = {{0.f,0.f,0.f,0.f},{0.f,0.f,0.f,0.f},{0.f,0.f,0.f,0.f},{0.f,0.f,0.f,0.f}};
#pragma unroll
  for (int k0 = 0; k0 < 192; k0 += 32) {
    half8_t a;
    if (k0 < 64) a = *(const half8_t*)(A0 + ro + k0);
    else if (k0 < 128) a = *(const half8_t*)(A1 + ro + (k0 - 64));
    else a = *(const half8_t*)(A2 + ro + (k0 - 128));
    half8_t b0 = *(const half8_t*)(Bp + k0);
    half8_t b1f = *(const half8_t*)(Bp + 16 * 192 + k0);
    half8_t b2f = *(const half8_t*)(Bp + 32 * 192 + k0);
    half8_t b3f = *(const half8_t*)(Bp + 48 * 192 + k0);
    acc[0] = __builtin_amdgcn_mfma_f32_16x16x32_f16(a, b0, acc[0], 0, 0, 0);
    acc[1] = __builtin_amdgcn_mfma_f32_16x16x32_f16(a, b1f, acc[1], 0, 0, 0);
    acc[2] = __builtin_amdgcn_mfma_f32_16x16x32_f16(a, b2f, acc[2], 0, 0, 0);
    acc[3] = __builtin_amdgcn_mfma_f32_16x16x32_f16(a, b3f, acc[3], 0, 0, 0);
  }
#pragma unroll
  for (int i = 0; i < 4; ++i) {
    int rr = rbase + quad * 4 + i;
    if (rr < N) {
#pragma unroll
      for (int t = 0; t < 4; ++t)
        outc[((size_t)rr << 6) + t * 16 + m] = (_Float16)fmaxf(acc[t][i] + bias[t * 16 + m], 0.f);
    }
  }
}

// ---------------- fused tail (row-local, NO gather): conv2-linear -> W3 -> head ----------------
__global__ __launch_bounds__(256) void k_tail(const _Float16* __restrict__ A0,
                                              const _Float16* __restrict__ A1,
                                              const _Float16* __restrict__ A2,
                                              const _Float16* __restrict__ w16,
                                              const float* __restrict__ bc2,
                                              const float* __restrict__ b3,
                                              const float* __restrict__ W4,
                                              const float* __restrict__ b4,
                                              float* __restrict__ out, int N) {
  __shared__ _Float16 Hs2[64][72];
  __shared__ float Hs3[64][65];
  const int tid = threadIdx.x;
  const int wave = tid >> 6;
  const int lane = tid & 63;
  const int m = lane & 15;
  const int quad = lane >> 4;
  const int rbase = blockIdx.x * 64 + wave * 16;
  int arow = rbase + m;
  arow = arow < N ? arow : N - 1;
  {
    const size_t ro = ((size_t)arow << 6) + quad * 8;
    const _Float16* Bp = w16 + WOFF_WC2 + (size_t)m * 192 + quad * 8;
    float4_t acc[4] = {{0.f,0.f,0.f,0.f},{0.f,0.f,0.f,0.f},{0.f,0.f,0.f,0.f},{0.f,0.f,0.f,0.f}};
#pragma unroll
    for (int k0 = 0; k0 < 192; k0 += 32) {
      half8_t a;
      if (k0 < 64) a = *(const half8_t*)(A0 + ro + k0);
      else if (k0 < 128) a = *(const half8_t*)(A1 + ro + (k0 - 64));
      else a = *(const half8_t*)(A2 + ro + (k0 - 128));
      half8_t b0 = *(const half8_t*)(Bp + k0);
      half8_t b1f = *(const half8_t*)(Bp + 16 * 192 + k0);
      half8_t b2f = *(const half8_t*)(Bp + 32 * 192 + k0);
      half8_t b3f = *(const half8_t*)(Bp + 48 * 192 + k0);
      acc[0] = __builtin_amdgcn_mfma_f32_16x16x32_f16(a, b0, acc[0], 0, 0, 0);
      acc[1] = __builtin_amdgcn_mfma_f32_16x16x32_f16(a, b1f, acc[1], 0, 0, 0);
      acc[2] = __builtin_amdgcn_mfma_f32_16x16x32_f16(a, b2f, acc[2], 0, 0, 0);
      acc[3] = __builtin_amdgcn_mfma_f32_16x16x32_f16(a, b3f, acc[3], 0, 0, 0);
    }
#pragma unroll
    for (int i = 0; i < 4; ++i)
#pragma unroll
      for (int t = 0; t < 4; ++t)
        Hs2[wave * 16 + quad * 4 + i][t * 16 + m] =
            (_Float16)fmaxf(acc[t][i] + bc2[t * 16 + m], 0.f);
  }
  __syncthreads();
  {
    const _Float16* Ap = &Hs2[wave * 16 + m][quad * 8];
    const _Float16* Bp = w16 + WOFF_W3 + (size_t)m * H + quad * 8;
    float4_t acc[4] = {{0.f,0.f,0.f,0.f},{0.f,0.f,0.f,0.f},{0.f,0.f,0.f,0.f},{0.f,0.f,0.f,0.f}};
#pragma unroll
    for (int k0 = 0; k0 < H; k0 += 32) {
      half8_t a = *(const half8_t*)(Ap + k0);
      half8_t b0 = *(const half8_t*)(Bp + k0);
      half8_t b1f = *(const half8_t*)(Bp + 16 * H + k0);
      half8_t b2f = *(const half8_t*)(Bp + 32 * H + k0);
      half8_t b3f = *(const half8_t*)(Bp + 48 * H + k0);
      acc[0] = __builtin_amdgcn_mfma_f32_16x16x32_f16(a, b0, acc[0], 0, 0, 0);
      acc[1] = __builtin_amdgcn_mfma_f32_16x16x32_f16(a, b1f, acc[1], 0, 0, 0);
      acc[2] = __builtin_amdgcn_mfma_f32_16x16x32_f16(a, b2f, acc[2], 0, 0, 0);
      acc[3] = __builtin_amdgcn_mfma_f32_16x16x32_f16(a, b3f, acc[3], 0, 0, 0);
    }
#pragma unroll
    for (int i = 0; i < 4; ++i)
#pragma unroll
      for (int t = 0; t < 4; ++t)
        Hs3[wave * 16 + quad * 4 + i][t * 16 + m] = fmaxf(acc[t][i] + b3[t * 16 + m], 0.f);
  }
  __syncthreads();
  if (tid < 128) {
    int r = tid >> 1;
    int c = tid & 1;
    int row = blockIdx.x * 64 + r;
    if (row < N) {
      const float* w4 = W4 + c * 64;
      float s = 0.f;
#pragma unroll
      for (int k = 0; k < 64; ++k) s = fmaf(Hs3[r][k], w4[k], s);
      out[(size_t)row * 2 + c] = s + b4[c];
    }
  }
}

extern "C" void kernel_launch(void* const* d_in, const int* in_sizes, int n_in,
                              void* d_out, int out_size, void* d_ws, size_t ws_size,
                              hipStream_t stream) {
  const float* in_feat = (const float*)d_in[0];
  const int* src = (const int*)d_in[1];
  const int* dst = (const int*)d_in[2];
  const float* W1 = (const float*)d_in[3];
  const float* b1 = (const float*)d_in[4];
  const float* W2 = (const float*)d_in[5];
  const float* b2 = (const float*)d_in[6];
  const float* Wc1 = (const float*)d_in[7];
  const float* bc1 = (const float*)d_in[8];
  const float* Wc2 = (const float*)d_in[9];
  const float* bc2 = (const float*)d_in[10];
  const float* W3 = (const float*)d_in[11];
  const float* b3 = (const float*)d_in[12];
  const float* W4 = (const float*)d_in[13];
  const float* b4 = (const float*)d_in[14];
  float* out = (float*)d_out;

  char* ws = (char*)d_ws;
  size_t o = 0;
  auto carve = [&](size_t bytes) -> void* {
    o = (o + 255) & ~(size_t)255;
    void* p = ws + o;
    o += bytes;
    return p;
  };
  int* cnt = (int*)carve((size_t)NN * 4);
  unsigned short* ell = (unsigned short*)carve((size_t)NN * ELLCAP * 2);  // 6.4 MB u16
  float* dinv32 = (float*)carve((size_t)NN * 4);
  _Float16* w16 = (_Float16*)carve((size_t)WTOT * 2);
  _Float16* X0c = (_Float16*)carve((size_t)NN * H * 2);   // conv1 X0 (unscaled)
  _Float16* X1c = (_Float16*)carve((size_t)NN * H * 2);   // conv1 X1
  _Float16* X2c = (_Float16*)carve((size_t)NN * H * 2);   // conv1 X2
  _Float16* Y0c = (_Float16*)carve((size_t)NN * H * 2);   // conv2 X0 (= conv1 out)
  _Float16* Y1c = (_Float16*)carve((size_t)NN * H * 2);
  _Float16* Y2c = (_Float16*)carve((size_t)NN * H * 2);
  (void)ws_size; (void)in_sizes; (void)n_in; (void)out_size;

  const int NB_W4 = (NN + 15) / 16;        // 3125: 4 nodes/wave, 4 waves/block
  const int NB_PREP = NB_FILL + NB_CVTW;   // 1020

  hipMemsetAsync(cnt, 0, (size_t)NN * 4, stream);
  // fillell(u16) + weight cvt
  k_prep<<<NB_PREP, 256, 0, stream>>>(src, dst, cnt, ell, W1, W2, Wc1, Wc2, W3, w16);
  // dinv32 build + entry MLP -> X0c
  k_mlp<<<NB_DINV + NB_G, 256, 0, stream>>>(in_feat, w16, b1, b2, cnt, dinv32, X0c, NN);
  // conv1: X1 = -A.X0
  k_spmm<<<NB_W4, 256, 0, stream>>>(X0c, (const _Float16*)nullptr, X1c, cnt, dinv32, ell, -1.f, 0, NN);
  // conv1: X2 = -2*A.X1 - X0
  k_spmm<<<NB_W4, 256, 0, stream>>>(X1c, X0c, X2c, cnt, dinv32, ell, -2.f, 1, NN);
  // conv1 linear -> Y0c
  k_gemm192<<<NB_G, 256, 0, stream>>>(X0c, X1c, X2c, w16 + WOFF_WC1, bc1, Y0c, NN);
  // conv2: Y1 = -A.Y0
  k_spmm<<<NB_W4, 256, 0, stream>>>(Y0c, (const _Float16*)nullptr, Y1c, cnt, dinv32, ell, -1.f, 0, NN);
  // conv2: Y2 = -2*A.Y1 - Y0
  k_spmm<<<NB_W4, 256, 0, stream>>>(Y1c, Y0c, Y2c, cnt, dinv32, ell, -2.f, 1, NN);
  // fused tail: conv2-linear -> W3 -> head
  k_tail<<<NB_G, 256, 0, stream>>>(Y0c, Y1c, Y2c, w16, bc2, b3, W4, b4, out, NN);
}